// Round 1
// baseline (807.639 us; speedup 1.0000x reference)
//
#include <hip/hip_runtime.h>

typedef unsigned long long u64;
typedef unsigned int u32;

#define CELL 64
#define CX 17
#define CY 10
#define NC (CX*CY)
#define NBLKC 512

__device__ __forceinline__ float clipc(float v) {
    return fminf(fmaxf(v, 1e-3f), 1.0f - 1e-3f);
}
__device__ __forceinline__ double wave_red_add(double v) {
    for (int o = 32; o > 0; o >>= 1) v += __shfl_xor(v, o, 64);
    return v;
}
__device__ __forceinline__ float wave_red_maxf(float v) {
    for (int o = 32; o > 0; o >>= 1) v = fmaxf(v, __shfl_xor(v, o, 64));
    return v;
}
__device__ __forceinline__ float wave_red_addf(float v) {
    for (int o = 32; o > 0; o >>= 1) v += __shfl_xor(v, o, 64);
    return v;
}

// ---------------------------------------------------------------------------
// kP: per-sample init + spatial cell -> gt bitmask table.
// grid = B blocks, 256 threads.
// ---------------------------------------------------------------------------
__global__ void kP(const float* __restrict__ annot, u64* __restrict__ tagG,
                   int* __restrict__ counters, int* __restrict__ firstValid,
                   u64* __restrict__ cellMasks, int B_, int M_) {
    int b = blockIdx.x, t = threadIdx.x;
    __shared__ int icx0[64], icx1[64], icy0[64], icy1[64], gv[64];
    if (t < 64) {
        int valid = 0, a0 = 0, a1 = 0, b0 = 0, b1 = 0;
        if (t < M_) {
            const float* g = annot + ((size_t)b * M_ + t) * 5;
            float x1 = g[0], y1 = g[1], x2 = g[2], y2 = g[3], lb = g[4];
            valid = (lb != -1.0f) ? 1 : 0;
            a0 = min(CX - 1, max(0, (int)(x1 * (1.0f / CELL))));
            a1 = min(CX - 1, max(0, (int)(x2 * (1.0f / CELL))));
            b0 = min(CY - 1, max(0, (int)(y1 * (1.0f / CELL))));
            b1 = min(CY - 1, max(0, (int)(y2 * (1.0f / CELL))));
        }
        icx0[t] = a0; icx1[t] = a1; icy0[t] = b0; icy1[t] = b1; gv[t] = valid;
        tagG[b * 64 + t] = 0ULL;               // ws is 0xAA-poisoned: init here
    }
    if (t == 0) counters[b] = 0;
    __syncthreads();
    if (t == 0) {
        int fv = -1;
        for (int m = 0; m < M_ && m < 64; ++m) if (gv[m]) { fv = m; break; }
        firstValid[b] = fv;
    }
    for (int c = t; c < NC; c += blockDim.x) {
        int cx = c % CX, cy = c / CX;
        u64 mask = 0;
        for (int m = 0; m < M_ && m < 64; ++m)
            if (gv[m] && cx >= icx0[m] && cx <= icx1[m] && cy >= icy0[m] && cy <= icy1[m])
                mask |= (1ULL << m);
        cellMasks[(size_t)b * NC + c] = mask;
    }
}

// ---------------------------------------------------------------------------
// kA: per-anchor candidate IoU, focal cls partial sums, positive list append,
//     per-(b,m) packed tag argmax (LDS pre-combine -> global atomicMax).
// grid = (nChunks, B), 256 threads.
// ---------------------------------------------------------------------------
__global__ __launch_bounds__(256) void kA(
    const float* __restrict__ anchors, const float* __restrict__ cls,
    const u64* __restrict__ cellMasks, const float* __restrict__ annot,
    const int* __restrict__ firstValid, u64* __restrict__ tagG,
    int* __restrict__ counters, double* __restrict__ partialsA,
    u32* __restrict__ plist, int A_, int C_, int M_, int nChunks) {
    int b = blockIdx.y, chunk = blockIdx.x, t = threadIdx.x;
    __shared__ float gx1[64], gy1[64], gx2[64], gy2[64], garea[64];
    __shared__ u64 cellM[NC];
    __shared__ u64 tagLds[64];
    __shared__ double wsum[4];
    __shared__ int wcnt[4], woff[4], blockBase;
    if (t < 64) {
        float x1 = 0, y1 = 0, x2 = 0, y2 = 0;
        if (t < M_) {
            const float* g = annot + ((size_t)b * M_ + t) * 5;
            x1 = g[0]; y1 = g[1]; x2 = g[2]; y2 = g[3];
        }
        gx1[t] = x1; gy1[t] = y1; gx2[t] = x2; gy2[t] = y2;
        garea[t] = (x2 - x1) * (y2 - y1);
        tagLds[t] = 0ULL;
    }
    for (int c = t; c < NC; c += 256) cellM[c] = cellMasks[(size_t)b * NC + c];
    __syncthreads();

    int a = chunk * 256 + t;
    bool inb = (a < A_);
    float4 an = make_float4(0, 0, 0, 0);
    if (inb) an = ((const float4*)anchors)[a];
    float aarea = (an.z - an.x) * (an.w - an.y);
    int fv = firstValid[b];
    // base of the row max: valid non-candidates have iou == 0, first valid m wins ties
    float best = (fv >= 0) ? 0.0f : -1.0f;
    int bidx = (fv >= 0) ? fv : 0;
    if (inb) {
        int cx0 = min(CX - 1, max(0, (int)(an.x * (1.0f / CELL))));
        int cx1 = min(CX - 1, max(0, (int)(an.z * (1.0f / CELL))));
        int cy0 = min(CY - 1, max(0, (int)(an.y * (1.0f / CELL))));
        int cy1 = min(CY - 1, max(0, (int)(an.w * (1.0f / CELL))));
        u64 mask = 0;
        for (int cy = cy0; cy <= cy1; ++cy)
            for (int cx = cx0; cx <= cx1; ++cx)
                mask |= cellM[cy * CX + cx];
        while (mask) {
            int m = __ffsll((unsigned long long)mask) - 1;
            mask &= mask - 1;
            float iw = fmaxf(fminf(an.z, gx2[m]) - fmaxf(an.x, gx1[m]), 0.0f);
            float ih = fmaxf(fminf(an.w, gy2[m]) - fmaxf(an.y, gy1[m]), 0.0f);
            float inter = iw * ih;
            float ua = fmaxf(aarea + garea[m] - inter, 1e-8f);
            float iou = inter / ua;
            if (iou > best) { best = iou; bidx = m; }  // ascending m => first-index ties
            if (iou >= 0.1f)
                atomicMax(&tagLds[m],
                          ((u64)__float_as_uint(iou) << 32) | (u64)(0xFFFFFFFFu - (u32)a));
        }
    }
    bool positive = inb && (best >= 0.5f);
    double cterm = 0.0;
    if (inb) {
        for (int c = 0; c < C_; ++c) {
            float v = clipc(cls[((size_t)b * A_ + a) * C_ + c]);
            float term = (c == 0 && positive)
                             ? (0.25f * (1.0f - v) * (1.0f - v) * (-logf(v)))
                             : (0.75f * v * v * (-logf(1.0f - v)));
            cterm += (double)term;
        }
    }
    // block-aggregated compact append of iou-positives
    u64 bm = __ballot(positive);
    int w = t >> 6;
    int rank = __builtin_amdgcn_mbcnt_hi((u32)(bm >> 32),
                                         __builtin_amdgcn_mbcnt_lo((u32)bm, 0));
    double s = wave_red_add(cterm);
    if ((t & 63) == 0) { wcnt[w] = (int)__popcll(bm); wsum[w] = s; }
    __syncthreads();
    if (t == 0) {
        int c0 = wcnt[0], c1 = wcnt[1], c2 = wcnt[2], c3 = wcnt[3];
        int tot = c0 + c1 + c2 + c3;
        woff[0] = 0; woff[1] = c0; woff[2] = c0 + c1; woff[3] = c0 + c1 + c2;
        blockBase = tot ? atomicAdd(&counters[b], tot) : 0;
        partialsA[(size_t)b * nChunks + chunk] = wsum[0] + wsum[1] + wsum[2] + wsum[3];
    }
    __syncthreads();
    if (positive)
        plist[(size_t)b * A_ + blockBase + woff[w] + rank] = (u32)a | ((u32)bidx << 20);
    if (t < 64) {
        u64 v = tagLds[t];
        if (v) atomicMax(&tagG[b * 64 + t], v);
    }
}

// ---------------------------------------------------------------------------
// kB: tag winners -> extra positives + cls correction. grid = B, 64 threads.
// ---------------------------------------------------------------------------
__global__ void kB(const float* __restrict__ anchors, const float* __restrict__ cls,
                   const float* __restrict__ annot, const u64* __restrict__ tagG,
                   int* __restrict__ counters, double* __restrict__ partialsB2,
                   u32* __restrict__ plist, int A_, int C_, int M_) {
    int b = blockIdx.x, t = threadIdx.x;
    __shared__ float gx1[64], gy1[64], gx2[64], gy2[64], garea[64];
    __shared__ int gv[64];
    __shared__ u32 qa[64];
    {
        float x1 = 0, y1 = 0, x2 = 0, y2 = 0; int valid = 0;
        if (t < M_) {
            const float* g = annot + ((size_t)b * M_ + t) * 5;
            x1 = g[0]; y1 = g[1]; x2 = g[2]; y2 = g[3];
            valid = (g[4] != -1.0f) ? 1 : 0;
        }
        gx1[t] = x1; gy1[t] = y1; gx2[t] = x2; gy2[t] = y2;
        garea[t] = (x2 - x1) * (y2 - y1); gv[t] = valid;
    }
    u64 v = tagG[b * 64 + t];
    bool qual = ((u32)(v >> 32)) >= 0x3DCCCCCDu;  // float bits of 0.1f
    u32 a = qual ? (0xFFFFFFFFu - (u32)v) : 0xFFFFFFFFu;
    qa[t] = a;
    __syncthreads();
    bool dup = false;
    if (qual)
        for (int m = 0; m < t; ++m)
            if (qa[m] == a) { dup = true; break; }
    bool proc = qual && !dup;
    double delta = 0.0;
    if (proc) {
        float4 an = ((const float4*)anchors)[a];
        float aarea = (an.z - an.x) * (an.w - an.y);
        float best = -INFINITY; int bidx = 0;
        for (int m = 0; m < M_ && m < 64; ++m) {
            float iou;
            if (gv[m]) {
                float iw = fmaxf(fminf(an.z, gx2[m]) - fmaxf(an.x, gx1[m]), 0.0f);
                float ih = fmaxf(fminf(an.w, gy2[m]) - fmaxf(an.y, gy1[m]), 0.0f);
                float inter = iw * ih;
                float ua = fmaxf(aarea + garea[m] - inter, 1e-8f);
                iou = inter / ua;
            } else iou = -1.0f;
            if (iou > best) { best = iou; bidx = m; }
        }
        if (best < 0.5f) {  // not already appended by kA
            int idx = atomicAdd(&counters[b], 1);
            plist[(size_t)b * A_ + idx] = a | ((u32)bidx << 20);
            float c0 = clipc(cls[((size_t)b * A_ + a) * C_ + 0]);
            float post = 0.25f * (1.0f - c0) * (1.0f - c0) * (-logf(c0));
            float negt = 0.75f * c0 * c0 * (-logf(1.0f - c0));
            delta = (double)post - (double)negt;
        }
    }
    double ds = wave_red_add(delta);
    if (t == 0) partialsB2[b] = ds;
}

// ---------------------------------------------------------------------------
// kC: one wave per positive anchor: femb NLL (logsumexp over F) + smooth-L1.
// grid = NBLKC, 256 threads (4 waves).
// ---------------------------------------------------------------------------
__global__ __launch_bounds__(256) void kC(
    const float* __restrict__ femb, const float* __restrict__ regr,
    const float* __restrict__ anchors, const float* __restrict__ annot,
    const float* __restrict__ stdv, const int* __restrict__ counters,
    const u32* __restrict__ plist, double* __restrict__ partialsC,
    int A_, int M_, int F_, int B_) {
    int t = threadIdx.x, w = t >> 6, lane = t & 63;
    __shared__ double accR[4], accF[4];
    float sd0 = stdv[0], sd1 = stdv[1], sd2 = stdv[2], sd3 = stdv[3];
    for (int b = 0; b < B_; ++b) {
        int cnt = counters[b];
        double rsum = 0.0, fsum = 0.0;
        for (int i = blockIdx.x * 4 + w; i < cnt; i += gridDim.x * 4) {
            u32 e = plist[(size_t)b * A_ + i];
            int a = (int)(e & 0xFFFFFu);
            int m = (int)(e >> 20);
            size_t rb = ((size_t)b * A_ + a) * (size_t)F_;
            float v0 = (lane < F_) ? femb[rb + lane] : -INFINITY;
            float v1 = (lane + 64 < F_) ? femb[rb + 64 + lane] : -INFINITY;
            float mx = wave_red_maxf(fmaxf(v0, v1));
            float ex = ((lane < F_) ? expf(v0 - mx) : 0.0f) +
                       ((lane + 64 < F_) ? expf(v1 - mx) : 0.0f);
            float ssum = wave_red_addf(ex);
            int label = (int)annot[((size_t)b * M_ + m) * 5 + 4];
            float xl = (label == lane) ? v0 : (label == lane + 64) ? v1 : -INFINITY;
            xl = wave_red_maxf(xl);
            if (lane == 0) {
                fsum += (double)(logf(ssum) + mx - xl);
                float4 an = ((const float4*)anchors)[a];
                float aw = an.z - an.x, ah = an.w - an.y;
                float acx = an.x + 0.5f * aw, acy = an.y + 0.5f * ah;
                const float* g = annot + ((size_t)b * M_ + m) * 5;
                float gw = g[2] - g[0], gh = g[3] - g[1];
                float gcx = g[0] + 0.5f * gw, gcy = g[1] + 0.5f * gh;
                gw = fmaxf(gw, 1.0f); gh = fmaxf(gh, 1.0f);
                float4 rg = ((const float4*)regr)[(size_t)b * A_ + a];
                float tt0 = ((gcx - acx) / aw) / sd0;
                float tt1 = ((gcy - acy) / ah) / sd1;
                float tt2 = logf(gw / aw) / sd2;
                float tt3 = logf(gh / ah) / sd3;
                float d0 = fabsf(tt0 - rg.x), d1 = fabsf(tt1 - rg.y);
                float d2 = fabsf(tt2 - rg.z), d3 = fabsf(tt3 - rg.w);
                const float th = 1.0f / 9.0f, hb = 0.5f / 9.0f;
                float r0 = (d0 <= th) ? 4.5f * d0 * d0 : d0 - hb;
                float r1 = (d1 <= th) ? 4.5f * d1 * d1 : d1 - hb;
                float r2 = (d2 <= th) ? 4.5f * d2 * d2 : d2 - hb;
                float r3 = (d3 <= th) ? 4.5f * d3 * d3 : d3 - hb;
                rsum += (double)(r0 + r1 + r2 + r3);
            }
        }
        if (lane == 0) { accR[w] = rsum; accF[w] = fsum; }
        __syncthreads();
        if (t == 0) {
            partialsC[((size_t)blockIdx.x * B_ + b) * 2 + 0] = accR[0] + accR[1] + accR[2] + accR[3];
            partialsC[((size_t)blockIdx.x * B_ + b) * 2 + 1] = accF[0] + accF[1] + accF[2] + accF[3];
        }
        __syncthreads();
    }
}

// ---------------------------------------------------------------------------
// kD: final deterministic reduction -> 3 scalars. grid = 1, 512 threads.
// ---------------------------------------------------------------------------
__global__ void kD(const double* __restrict__ partialsA, const double* __restrict__ partialsB2,
                   const double* __restrict__ partialsC, const int* __restrict__ counters,
                   float* __restrict__ out, int nChunks, int B_) {
    int t = threadIdx.x, w = t >> 6, lane = t & 63;
    __shared__ double res[48];
    for (int bb = w; bb < B_; bb += 8) {
        double s = 0.0;
        for (int i = lane; i < nChunks; i += 64) s += partialsA[(size_t)bb * nChunks + i];
        s = wave_red_add(s);
        if (lane == 0) res[bb] = s;
        double r = 0.0, f = 0.0;
        for (int i = lane; i < NBLKC; i += 64) {
            r += partialsC[((size_t)i * B_ + bb) * 2 + 0];
            f += partialsC[((size_t)i * B_ + bb) * 2 + 1];
        }
        r = wave_red_add(r);
        f = wave_red_add(f);
        if (lane == 0) { res[16 + bb] = r; res[32 + bb] = f; }
    }
    __syncthreads();
    if (t == 0) {
        double cm = 0, rm = 0, fm = 0;
        for (int b = 0; b < B_; ++b) {
            int np = counters[b];
            float npf = (float)np;
            double clsv = (res[b] + partialsB2[b]) / (double)fmaxf(npf, 1.0f);
            double regv = (np > 0) ? res[16 + b] / (double)fmaxf(npf * 4.0f, 1.0f) : 0.0;
            double fev  = (np > 0) ? res[32 + b] / (double)fmaxf(npf, 1.0f) : 0.0;
            cm += clsv; rm += regv; fm += fev;
        }
        out[0] = (float)(cm / B_);
        out[1] = (float)(rm / B_);
        out[2] = (float)(fm / B_);
    }
}

extern "C" void kernel_launch(void* const* d_in, const int* in_sizes, int n_in,
                              void* d_out, int out_size, void* d_ws, size_t ws_size,
                              hipStream_t stream) {
    const float* cls     = (const float*)d_in[0];
    const float* regr    = (const float*)d_in[1];
    const float* anchors = (const float*)d_in[2];
    const float* annot   = (const float*)d_in[3];
    const float* stdv    = (const float*)d_in[4];
    const float* femb    = (const float*)d_in[5];

    int A = in_sizes[2] / 4;                 // anchors (1,A,4)
    int B = in_sizes[1] / (4 * A);           // regressions (B,A,4)
    int C = in_sizes[0] / (B * A);           // classifications (B,A,C)
    int M = in_sizes[3] / (5 * B);           // annotations (B,M,5), M<=64 assumed
    int F = (int)((size_t)in_sizes[5] / ((size_t)B * A));  // femb (B,A,F), F<=128
    int nChunks = (A + 255) / 256;

    char* p = (char*)d_ws;
    auto alloc = [&](size_t bytes) {
        char* r = p;
        p += (bytes + 255) & ~(size_t)255;
        return r;
    };
    u64* tagG         = (u64*)alloc((size_t)B * 64 * 8);
    u64* cellMasks    = (u64*)alloc((size_t)B * NC * 8);
    double* partialsA = (double*)alloc((size_t)B * nChunks * 8);
    double* partialsB2= (double*)alloc((size_t)B * 8);
    double* partialsC = (double*)alloc((size_t)NBLKC * B * 2 * 8);
    int* counters     = (int*)alloc((size_t)B * 4);
    int* firstValid   = (int*)alloc((size_t)B * 4);
    u32* plist        = (u32*)alloc((size_t)B * A * 4);

    hipLaunchKernelGGL(kP, dim3(B), dim3(256), 0, stream,
                       annot, tagG, counters, firstValid, cellMasks, B, M);
    hipLaunchKernelGGL(kA, dim3(nChunks, B), dim3(256), 0, stream,
                       anchors, cls, cellMasks, annot, firstValid, tagG, counters,
                       partialsA, plist, A, C, M, nChunks);
    hipLaunchKernelGGL(kB, dim3(B), dim3(64), 0, stream,
                       anchors, cls, annot, tagG, counters, partialsB2, plist, A, C, M);
    hipLaunchKernelGGL(kC, dim3(NBLKC), dim3(256), 0, stream,
                       femb, regr, anchors, annot, stdv, counters, plist, partialsC,
                       A, M, F, B);
    hipLaunchKernelGGL(kD, dim3(1), dim3(512), 0, stream,
                       partialsA, partialsB2, partialsC, counters, (float*)d_out,
                       nChunks, B);
}